// Round 1
// baseline (76.090 us; speedup 1.0000x reference)
//
#include <hip/hip_runtime.h>

#define KN 4096
#define NSAMP 16384

// Compute the 4 multilinear coefficients from one 16-wide softmax row.
__device__ __forceinline__ void coeffs_from_w(const float* __restrict__ w,
                                              float& c0, float& ca, float& cb, float& cab) {
    float m = w[0];
    #pragma unroll
    for (int j = 1; j < 16; ++j) m = fmaxf(m, w[j]);
    float p[16];
    float s = 0.0f;
    #pragma unroll
    for (int j = 0; j < 16; ++j) { p[j] = expf(w[j] - m); s += p[j]; }
    #pragma unroll
    for (int j = 0; j < 16; ++j) p[j] = p[j] / s;
    ca  = p[2] + p[3] + p[6] + p[7] - p[8] - p[9] - p[12] - p[13];
    cb  = p[4] + p[5] + p[6] + p[7] - p[8] - p[9] - p[10] - p[11];
    cab = p[1] - p[2] - p[4] - 2.0f*p[6] - p[7] + p[8] + 2.0f*p[9] + p[11] + p[13] - p[14];
    c0  = p[8] + p[9] + p[10] + p[11] + p[12] + p[13] + p[14] + p[15];
}

// One block per 4-bit input pattern: run the full 4-layer network, reduce to
// the two class sums, write table[pat][2].
__global__ __launch_bounds__(256) void build_table(
    const float* __restrict__ w0, const float* __restrict__ wsG,
    const int* __restrict__ ia0, const int* __restrict__ ib0,
    const int* __restrict__ ia, const int* __restrict__ ib,
    float* __restrict__ table) {
    __shared__ float h[2][KN];
    __shared__ float red[2][256];
    const int pat = blockIdx.x;
    const int tid = threadIdx.x;

    // Layer 0: inputs are the 4 pattern bits.
    for (int k = tid; k < KN; k += 256) {
        float w[16];
        const float4* wr = (const float4*)(w0 + (size_t)k * 16);
        float4 v0 = wr[0], v1 = wr[1], v2 = wr[2], v3 = wr[3];
        w[0]=v0.x; w[1]=v0.y; w[2]=v0.z; w[3]=v0.w;
        w[4]=v1.x; w[5]=v1.y; w[6]=v1.z; w[7]=v1.w;
        w[8]=v2.x; w[9]=v2.y; w[10]=v2.z; w[11]=v2.w;
        w[12]=v3.x; w[13]=v3.y; w[14]=v3.z; w[15]=v3.w;
        float c0, ca, cb, cab;
        coeffs_from_w(w, c0, ca, cb, cab);
        float a = (float)((pat >> ia0[k]) & 1);
        float b = (float)((pat >> ib0[k]) & 1);
        h[0][k] = c0 + ca * a + cb * b + cab * (a * b);
    }
    __syncthreads();

    int cur = 0;
    for (int l = 0; l < 3; ++l) {
        const float* wl = wsG + (size_t)l * KN * 16;
        const int* ial = ia + l * KN;
        const int* ibl = ib + l * KN;
        for (int k = tid; k < KN; k += 256) {
            float w[16];
            const float4* wr = (const float4*)(wl + (size_t)k * 16);
            float4 v0 = wr[0], v1 = wr[1], v2 = wr[2], v3 = wr[3];
            w[0]=v0.x; w[1]=v0.y; w[2]=v0.z; w[3]=v0.w;
            w[4]=v1.x; w[5]=v1.y; w[6]=v1.z; w[7]=v1.w;
            w[8]=v2.x; w[9]=v2.y; w[10]=v2.z; w[11]=v2.w;
            w[12]=v3.x; w[13]=v3.y; w[14]=v3.z; w[15]=v3.w;
            float c0, ca, cb, cab;
            coeffs_from_w(w, c0, ca, cb, cab);
            float a = h[cur][ial[k]];
            float b = h[cur][ibl[k]];
            h[1 - cur][k] = c0 + ca * a + cb * b + cab * (a * b);
        }
        __syncthreads();
        cur = 1 - cur;
    }

    // Class reduction: k in [0,2048) -> class 0, [2048,4096) -> class 1. TAU=1.
    float s0 = 0.0f, s1 = 0.0f;
    for (int k = tid; k < KN; k += 256) {
        if (k < KN / 2) s0 += h[cur][k]; else s1 += h[cur][k];
    }
    red[0][tid] = s0;
    red[1][tid] = s1;
    __syncthreads();
    for (int off = 128; off > 0; off >>= 1) {
        if (tid < off) {
            red[0][tid] += red[0][tid + off];
            red[1][tid] += red[1][tid + off];
        }
        __syncthreads();
    }
    if (tid == 0) {
        table[pat * 2 + 0] = red[0][0];
        table[pat * 2 + 1] = red[1][0];
    }
}

// Per-sample: pattern lookup twice with the reference's exact update logic.
__global__ __launch_bounds__(256) void classify(
    const float* __restrict__ x, const float* __restrict__ table_g,
    float* __restrict__ out) {
    __shared__ float table[32];
    if (threadIdx.x < 32) table[threadIdx.x] = table_g[threadIdx.x];
    __syncthreads();
    int n = blockIdx.x * 256 + threadIdx.x;
    if (n >= NSAMP) return;
    float2 xv = ((const float2*)x)[n];
    float mx[4] = { xv.x, xv.y, -xv.x, -xv.y };
    int p0 = 0;
    float ivf[4];
    #pragma unroll
    for (int i = 0; i < 4; ++i) {
        int b = mx[i] > 0.0f;
        ivf[i] = (float)b;
        p0 |= b << i;
    }
    float r0 = table[p0 * 2 + 0];
    float r1 = table[p0 * 2 + 1];
    // argmax over {r0, r1}; tie -> index 0
    int lastl = (r1 > r0) ? 1 : 0;
    float thresh = lastl ? 0.5f : -0.5f;
    int p1 = 0;
    #pragma unroll
    for (int i = 0; i < 4; ++i) {
        bool upd = (ivf[i] == r0) || (ivf[i] == r1);  // any(flags == 0)
        int bit = upd ? (int)(mx[i] > thresh) : (int)ivf[i];
        p1 |= bit << i;
    }
    float2 o;
    o.x = table[p1 * 2 + 0];
    o.y = table[p1 * 2 + 1];
    ((float2*)out)[n] = o;
}

extern "C" void kernel_launch(void* const* d_in, const int* in_sizes, int n_in,
                              void* d_out, int out_size, void* d_ws, size_t ws_size,
                              hipStream_t stream) {
    const float* x   = (const float*)d_in[0];
    const float* w0  = (const float*)d_in[1];
    const float* wsG = (const float*)d_in[2];
    const int* ia0   = (const int*)d_in[3];
    const int* ib0   = (const int*)d_in[4];
    const int* ia    = (const int*)d_in[5];
    const int* ib    = (const int*)d_in[6];
    float* table = (float*)d_ws;  // 32 floats

    build_table<<<16, 256, 0, stream>>>(w0, wsG, ia0, ib0, ia, ib, table);
    classify<<<NSAMP / 256, 256, 0, stream>>>(x, table, (float*)d_out);
}

// Round 2
// 18.241 us; speedup vs baseline: 4.1715x; 4.1715x over previous
//
#include <hip/hip_runtime.h>

#define KN 4096
#define NSAMP 16384
#define NNEUR (4 * KN)   // layer0 + 3 hidden layers

// Compute the 4 multilinear coefficients from one 16-wide softmax row.
__device__ __forceinline__ void coeffs_from_w(const float* __restrict__ w,
                                              float& c0, float& ca, float& cb, float& cab) {
    float m = w[0];
    #pragma unroll
    for (int j = 1; j < 16; ++j) m = fmaxf(m, w[j]);
    float p[16];
    float s = 0.0f;
    #pragma unroll
    for (int j = 0; j < 16; ++j) { p[j] = expf(w[j] - m); s += p[j]; }
    float inv = 1.0f / s;
    #pragma unroll
    for (int j = 0; j < 16; ++j) p[j] *= inv;
    ca  = p[2] + p[3] + p[6] + p[7] - p[8] - p[9] - p[12] - p[13];
    cb  = p[4] + p[5] + p[6] + p[7] - p[8] - p[9] - p[10] - p[11];
    cab = p[1] - p[2] - p[4] - 2.0f*p[6] - p[7] + p[8] + 2.0f*p[9] + p[11] + p[13] - p[14];
    c0  = p[8] + p[9] + p[10] + p[11] + p[12] + p[13] + p[14] + p[15];
}

// One thread per neuron (all 4 layers): softmax -> 4 coeffs, written once.
// Removes the 16x-redundant expf chains from the per-pattern critical path.
__global__ __launch_bounds__(256) void compute_coeffs(
    const float* __restrict__ w0, const float* __restrict__ wsG,
    float4* __restrict__ coeffs) {
    int g = blockIdx.x * 256 + threadIdx.x;
    if (g >= NNEUR) return;
    const float* wp = (g < KN) ? (w0 + (size_t)g * 16)
                               : (wsG + (size_t)(g - KN) * 16);
    float w[16];
    const float4* wr = (const float4*)wp;
    float4 v0 = wr[0], v1 = wr[1], v2 = wr[2], v3 = wr[3];
    w[0]=v0.x; w[1]=v0.y; w[2]=v0.z; w[3]=v0.w;
    w[4]=v1.x; w[5]=v1.y; w[6]=v1.z; w[7]=v1.w;
    w[8]=v2.x; w[9]=v2.y; w[10]=v2.z; w[11]=v2.w;
    w[12]=v3.x; w[13]=v3.y; w[14]=v3.z; w[15]=v3.w;
    float c0, ca, cb, cab;
    coeffs_from_w(w, c0, ca, cb, cab);
    coeffs[g] = make_float4(c0, ca, cb, cab);
}

// One block per 4-bit input pattern; 1024 threads so each layer is 4 fully
// unrolled independent neuron evals per thread (loads hoisted together).
__global__ __launch_bounds__(1024) void build_table(
    const float4* __restrict__ coeffs,
    const int* __restrict__ ia0, const int* __restrict__ ib0,
    const int* __restrict__ ia, const int* __restrict__ ib,
    float* __restrict__ table) {
    __shared__ float h0[KN];
    __shared__ float h1[KN];
    __shared__ float red[2][16];
    const int pat = blockIdx.x;
    const int tid = threadIdx.x;

    // Layer 0: inputs are the 4 pattern bits.
    #pragma unroll
    for (int i = 0; i < 4; ++i) {
        int k = tid + i * 1024;
        float4 c = coeffs[k];
        float a = (float)((pat >> ia0[k]) & 1);
        float b = (float)((pat >> ib0[k]) & 1);
        h0[k] = c.x + c.y * a + c.z * b + c.w * (a * b);
    }
    __syncthreads();

    // Hidden layers with compile-time-constant src/dst LDS buffers.
#define LAYER(L, SRC, DST)                                                    \
    {                                                                         \
        const int* ial = ia + (L) * KN;                                       \
        const int* ibl = ib + (L) * KN;                                       \
        _Pragma("unroll")                                                     \
        for (int i = 0; i < 4; ++i) {                                         \
            int k = tid + i * 1024;                                           \
            float4 c = coeffs[((L) + 1) * KN + k];                            \
            float a = SRC[ial[k]];                                            \
            float b = SRC[ibl[k]];                                            \
            DST[k] = c.x + c.y * a + c.z * b + c.w * (a * b);                 \
        }                                                                     \
        __syncthreads();                                                      \
    }
    LAYER(0, h0, h1)
    LAYER(1, h1, h0)
    LAYER(2, h0, h1)
#undef LAYER

    // Class sums: k in [0,2048) -> class 0, else class 1. TAU = 1.
    float s0 = h1[tid] + h1[tid + 1024];
    float s1 = h1[tid + 2048] + h1[tid + 3072];
    #pragma unroll
    for (int off = 32; off > 0; off >>= 1) {
        s0 += __shfl_down(s0, off, 64);
        s1 += __shfl_down(s1, off, 64);
    }
    int wid = tid >> 6, lane = tid & 63;
    if (lane == 0) { red[0][wid] = s0; red[1][wid] = s1; }
    __syncthreads();
    if (tid == 0) {
        float t0 = 0.0f, t1 = 0.0f;
        #pragma unroll
        for (int wq = 0; wq < 16; ++wq) { t0 += red[0][wq]; t1 += red[1][wq]; }
        table[pat * 2 + 0] = t0;
        table[pat * 2 + 1] = t1;
    }
}

// Per-sample: pattern lookup twice with the reference's exact update logic.
__global__ __launch_bounds__(256) void classify(
    const float* __restrict__ x, const float* __restrict__ table_g,
    float* __restrict__ out) {
    __shared__ float table[32];
    if (threadIdx.x < 32) table[threadIdx.x] = table_g[threadIdx.x];
    __syncthreads();
    int n = blockIdx.x * 256 + threadIdx.x;
    if (n >= NSAMP) return;
    float2 xv = ((const float2*)x)[n];
    float mx[4] = { xv.x, xv.y, -xv.x, -xv.y };
    int p0 = 0;
    float ivf[4];
    #pragma unroll
    for (int i = 0; i < 4; ++i) {
        int b = mx[i] > 0.0f;
        ivf[i] = (float)b;
        p0 |= b << i;
    }
    float r0 = table[p0 * 2 + 0];
    float r1 = table[p0 * 2 + 1];
    // argmax over {r0, r1}; tie -> index 0
    int lastl = (r1 > r0) ? 1 : 0;
    float thresh = lastl ? 0.5f : -0.5f;
    int p1 = 0;
    #pragma unroll
    for (int i = 0; i < 4; ++i) {
        bool upd = (ivf[i] == r0) || (ivf[i] == r1);  // any(flags == 0)
        int bit = upd ? (int)(mx[i] > thresh) : (int)ivf[i];
        p1 |= bit << i;
    }
    float2 o;
    o.x = table[p1 * 2 + 0];
    o.y = table[p1 * 2 + 1];
    ((float2*)out)[n] = o;
}

extern "C" void kernel_launch(void* const* d_in, const int* in_sizes, int n_in,
                              void* d_out, int out_size, void* d_ws, size_t ws_size,
                              hipStream_t stream) {
    const float* x   = (const float*)d_in[0];
    const float* w0  = (const float*)d_in[1];
    const float* wsG = (const float*)d_in[2];
    const int* ia0   = (const int*)d_in[3];
    const int* ib0   = (const int*)d_in[4];
    const int* ia    = (const int*)d_in[5];
    const int* ib    = (const int*)d_in[6];

    float* table   = (float*)d_ws;                    // 32 floats
    float4* coeffs = (float4*)((char*)d_ws + 128);    // 16384 float4 = 256 KB

    compute_coeffs<<<(NNEUR + 255) / 256, 256, 0, stream>>>(w0, wsG, coeffs);
    build_table<<<16, 1024, 0, stream>>>(coeffs, ia0, ib0, ia, ib, table);
    classify<<<NSAMP / 256, 256, 0, stream>>>(x, table, (float*)d_out);
}